// Round 1
// baseline (833.774 us; speedup 1.0000x reference)
//
#include <hip/hip_runtime.h>

#define N_NODES 100000
#define N_EDGES 3200000
#define IN_DIM  512
#define HIDDEN  16
#define NCLS    7

#define CHUNK   1024
#define NCHUNK  ((N_NODES + CHUNK - 1) / CHUNK)   // 98

// ---------------- counting sort: histogram ----------------
__global__ __launch_bounds__(256) void k_zero_cnt(int* __restrict__ cnt) {
    int i = blockIdx.x * 256 + threadIdx.x;
    if (i < N_NODES) cnt[i] = 0;
}

__global__ __launch_bounds__(256) void k_count(const int* __restrict__ dst,
                                               int* __restrict__ cnt) {
    int e = blockIdx.x * 256 + threadIdx.x;
    if (e < N_EDGES) atomicAdd(&cnt[dst[e]], 1);
}

// ---------------- counting sort: 3-phase prefix scan ----------------
__global__ __launch_bounds__(256) void k_chunksum(const int* __restrict__ cnt,
                                                  int* __restrict__ csum) {
    __shared__ int sred[256];
    int c = blockIdx.x, tid = threadIdx.x;
    int i0 = c * CHUNK + tid * 4;
    int s = 0;
#pragma unroll
    for (int k = 0; k < 4; ++k) {
        int i = i0 + k;
        if (i < N_NODES) s += cnt[i];
    }
    sred[tid] = s;
    __syncthreads();
    for (int off = 128; off > 0; off >>= 1) {
        if (tid < off) sred[tid] += sred[tid + off];
        __syncthreads();
    }
    if (tid == 0) csum[c] = sred[0];
}

__global__ void k_chunkscan(const int* __restrict__ csum, int* __restrict__ coff,
                            int* __restrict__ rowstart) {
    if (blockIdx.x == 0 && threadIdx.x == 0) {
        int run = 0;
        for (int c = 0; c < NCHUNK; ++c) { coff[c] = run; run += csum[c]; }
        rowstart[N_NODES] = run;   // == N_EDGES
    }
}

// exclusive scan within chunk + chunk offset; also emits cursor copy and dinv
__global__ __launch_bounds__(256) void k_scan(const int* __restrict__ cnt,
                                              const int* __restrict__ coff,
                                              int* __restrict__ rowstart,
                                              int* __restrict__ cursor,
                                              float* __restrict__ dinv) {
    __shared__ int ssum[256];
    int c = blockIdx.x, tid = threadIdx.x;
    int i0 = c * CHUNK + tid * 4;
    int a[4];
#pragma unroll
    for (int k = 0; k < 4; ++k) {
        int i = i0 + k;
        a[k] = (i < N_NODES) ? cnt[i] : 0;
    }
    int s = a[0] + a[1] + a[2] + a[3];
    ssum[tid] = s;
    __syncthreads();
    // Hillis-Steele inclusive scan over thread sums
    for (int off = 1; off < 256; off <<= 1) {
        int t = (tid >= off) ? ssum[tid - off] : 0;
        __syncthreads();
        ssum[tid] += t;
        __syncthreads();
    }
    int run = ssum[tid] - s + coff[c];   // exclusive prefix for this thread
#pragma unroll
    for (int k = 0; k < 4; ++k) {
        int i = i0 + k;
        if (i < N_NODES) {
            rowstart[i] = run;
            cursor[i]   = run;
            dinv[i]     = rsqrtf((float)(a[k] + 1));  // +1 self-loop
            run += a[k];
        }
    }
}

// ---------------- counting sort: scatter src into CSR ----------------
__global__ __launch_bounds__(256) void k_scatter(const int* __restrict__ src,
                                                 const int* __restrict__ dst,
                                                 int* __restrict__ cursor,
                                                 int* __restrict__ csr_src) {
    int e = blockIdx.x * 256 + threadIdx.x;
    if (e >= N_EDGES) return;
    int d = dst[e];
    int pos = atomicAdd(&cursor[d], 1);
    csr_src[pos] = src[e];
}

// ---------------- layer-1 GEMM: h1s = (x @ W1) * dinv[n] ----------------
__global__ __launch_bounds__(256) void k_gemm1(
    const float* __restrict__ x, const float* __restrict__ W1,
    const float* __restrict__ dinv, float* __restrict__ h1s) {
    __shared__ float Xs[256 * 33];
    const int tid = threadIdx.x;
    const int n0  = blockIdx.x * 256;
    const int n   = n0 + tid;

    float acc[16];
#pragma unroll
    for (int j = 0; j < 16; ++j) acc[j] = 0.f;

    for (int kc = 0; kc < IN_DIM; kc += 32) {
        __syncthreads();
#pragma unroll
        for (int r = 0; r < 8; ++r) {
            int flat = r * 256 + tid;
            int row  = flat >> 3;
            int col  = (flat & 7) << 2;
            int gn   = n0 + row;
            if (gn < N_NODES) {
                const float4 v = *(const float4*)(x + (size_t)gn * IN_DIM + kc + col);
                float* d = &Xs[row * 33 + col];
                d[0] = v.x; d[1] = v.y; d[2] = v.z; d[3] = v.w;
            }
        }
        __syncthreads();
        if (n < N_NODES) {
#pragma unroll
            for (int i = 0; i < 32; ++i) {
                float xv = Xs[tid * 33 + i];
                const float* wr = W1 + (size_t)(kc + i) * 16;
#pragma unroll
                for (int j = 0; j < 16; ++j) acc[j] = fmaf(xv, wr[j], acc[j]);
            }
        }
    }

    if (n < N_NODES) {
        float di = dinv[n];
#pragma unroll
        for (int j = 0; j < 16; j += 4) {
            *(float4*)(h1s + (size_t)n * 16 + j) =
                make_float4(acc[j] * di, acc[j+1] * di, acc[j+2] * di, acc[j+3] * di);
        }
    }
}

// ---------------- layer-1 gather-aggregate + bias + relu ----------------
// 16 lanes per node; agg1[d] = dinv[d]*(h1s[d] + sum h1s[src]); z = relu(agg1+b1)
__global__ __launch_bounds__(256) void k_agg1(
    const int* __restrict__ rowstart, const int* __restrict__ csr_src,
    const float* __restrict__ h1s, const float* __restrict__ dinv,
    const float* __restrict__ b1, float* __restrict__ z) {
    int gid = blockIdx.x * 256 + threadIdx.x;
    int g = gid >> 4, j = gid & 15;
    bool valid = g < N_NODES;
    int n = valid ? g : (N_NODES - 1);
    int start = rowstart[n], end = rowstart[n + 1];
    float acc = h1s[(size_t)n * 16 + j];   // self-loop term
#pragma unroll 4
    for (int i = start; i < end; ++i) {
        int s = csr_src[i];
        acc += h1s[(size_t)s * 16 + j];    // 16 lanes -> one 64B line
    }
    if (valid) {
        float v = dinv[n] * acc + b1[j];
        z[(size_t)n * 16 + j] = fmaxf(v, 0.f);
    }
}

// ---------------- layer-2 GEMM: h2s = (z @ W2) * dinv, padded stride 8 ----------------
__global__ __launch_bounds__(256) void k_layer2(
    const float* __restrict__ z, const float* __restrict__ W2,
    const float* __restrict__ dinv, float* __restrict__ h2s) {
    int n = blockIdx.x * 256 + threadIdx.x;
    if (n >= N_NODES) return;
    float zv[16];
#pragma unroll
    for (int k = 0; k < 16; k += 4) {
        float4 v = *(const float4*)(z + (size_t)n * 16 + k);
        zv[k] = v.x; zv[k+1] = v.y; zv[k+2] = v.z; zv[k+3] = v.w;
    }
    float di = dinv[n];
    float o[8];
#pragma unroll
    for (int jj = 0; jj < 7; ++jj) {
        float a = 0.f;
#pragma unroll
        for (int k = 0; k < 16; ++k) a = fmaf(zv[k], W2[k * 7 + jj], a);
        o[jj] = a * di;
    }
    o[7] = 0.f;
    *(float4*)(h2s + (size_t)n * 8 + 0) = make_float4(o[0], o[1], o[2], o[3]);
    *(float4*)(h2s + (size_t)n * 8 + 4) = make_float4(o[4], o[5], o[6], o[7]);
}

// ---------------- layer-2 gather-aggregate + bias + log_softmax ----------------
// 8 lanes per node (j<7 real classes, slot 7 is zero padding)
__global__ __launch_bounds__(256) void k_agg2(
    const int* __restrict__ rowstart, const int* __restrict__ csr_src,
    const float* __restrict__ h2s, const float* __restrict__ dinv,
    const float* __restrict__ b2, float* __restrict__ out) {
    int gid = blockIdx.x * 256 + threadIdx.x;
    int g = gid >> 3, j = gid & 7;
    bool valid = g < N_NODES;
    int n = valid ? g : (N_NODES - 1);
    int start = rowstart[n], end = rowstart[n + 1];
    float acc = h2s[(size_t)n * 8 + j];    // self-loop term (slot 7 reads 0)
#pragma unroll 4
    for (int i = start; i < end; ++i) {
        int s = csr_src[i];
        acc += h2s[(size_t)s * 8 + j];     // 8 lanes -> one 32B segment
    }
    float v = dinv[n] * acc + ((j < 7) ? b2[j] : -1e30f);
    // max over the 8-lane group
    float m = v;
    m = fmaxf(m, __shfl_xor(m, 1));
    m = fmaxf(m, __shfl_xor(m, 2));
    m = fmaxf(m, __shfl_xor(m, 4));
    float e = (j < 7) ? expf(v - m) : 0.f;
    float ssum = e;
    ssum += __shfl_xor(ssum, 1);
    ssum += __shfl_xor(ssum, 2);
    ssum += __shfl_xor(ssum, 4);
    float ls = logf(ssum) + m;
    if (valid && j < 7) out[(size_t)n * 7 + j] = v - ls;
}

extern "C" void kernel_launch(void* const* d_in, const int* in_sizes, int n_in,
                              void* d_out, int out_size, void* d_ws, size_t ws_size,
                              hipStream_t stream) {
    const float* x  = (const float*)d_in[0];
    const int*   ei = (const int*)d_in[1];
    const float* W1 = (const float*)d_in[2];
    const float* b1 = (const float*)d_in[3];
    const float* W2 = (const float*)d_in[4];
    const float* b2 = (const float*)d_in[5];
    float* out = (float*)d_out;

    const int* src = ei;             // edge_index[0]
    const int* dst = ei + N_EDGES;   // edge_index[1]

    char* ws = (char*)d_ws;
    size_t o = 0;
    auto alloc = [&](size_t bytes) -> void* {
        void* p = ws + o;
        o = (o + bytes + 255) & ~(size_t)255;
        return p;
    };
    int*   cnt      = (int*)alloc((size_t)N_NODES * 4);
    int*   rowstart = (int*)alloc(((size_t)N_NODES + 1) * 4);
    int*   cursor   = (int*)alloc((size_t)N_NODES * 4);
    float* dinv     = (float*)alloc((size_t)N_NODES * 4);
    int*   csum     = (int*)alloc((size_t)NCHUNK * 4);
    int*   coff     = (int*)alloc((size_t)NCHUNK * 4);
    int*   csr_src  = (int*)alloc((size_t)N_EDGES * 4);
    float* h1s      = (float*)alloc((size_t)N_NODES * 16 * 4);
    float* z        = (float*)alloc((size_t)N_NODES * 16 * 4);
    float* h2s      = (float*)alloc((size_t)N_NODES * 8 * 4);

    const int nb_n = (N_NODES + 255) / 256;
    const int nb_e = (N_EDGES + 255) / 256;

    k_zero_cnt <<<nb_n, 256, 0, stream>>>(cnt);
    k_count    <<<nb_e, 256, 0, stream>>>(dst, cnt);
    k_chunksum <<<NCHUNK, 256, 0, stream>>>(cnt, csum);
    k_chunkscan<<<1, 64, 0, stream>>>(csum, coff, rowstart);
    k_scan     <<<NCHUNK, 256, 0, stream>>>(cnt, coff, rowstart, cursor, dinv);
    k_scatter  <<<nb_e, 256, 0, stream>>>(src, dst, cursor, csr_src);
    k_gemm1    <<<nb_n, 256, 0, stream>>>(x, W1, dinv, h1s);
    k_agg1     <<<(N_NODES * 16 + 255) / 256, 256, 0, stream>>>(rowstart, csr_src, h1s, dinv, b1, z);
    k_layer2   <<<nb_n, 256, 0, stream>>>(z, W2, dinv, h2s);
    k_agg2     <<<(N_NODES * 8 + 255) / 256, 256, 0, stream>>>(rowstart, csr_src, h2s, dinv, b2, out);
}

// Round 2
// 515.697 us; speedup vs baseline: 1.6168x; 1.6168x over previous
//
#include <hip/hip_runtime.h>

#define N_NODES 100000
#define N_EDGES 3200000
#define IN_DIM  512
#define HIDDEN  16
#define NCLS    7

#define BSH     9
#define BNODES  512                                  // nodes per bucket
#define NB      ((N_NODES + BNODES - 1) / BNODES)    // 196 buckets

#define EPB1    8192                                 // edges/block, k_bcount
#define NBLK1   ((N_EDGES + EPB1 - 1) / EPB1)        // 391
#define EPB2    4096                                 // edges/block, k_bscatter
#define NBLK2   ((N_EDGES + EPB2 - 1) / EPB2)        // 782

// ---------------- init ----------------
__global__ void k_zero(int* __restrict__ bcnt, int* __restrict__ rowstart) {
    int i = threadIdx.x;
    bcnt[i] = 0;                       // 256 entries (>= NB)
    if (i == 0) rowstart[N_NODES] = N_EDGES;
}

// ---------------- coarse bucket histogram (per-block LDS, few global atomics) ----------------
__global__ __launch_bounds__(256) void k_bcount(const int* __restrict__ dst,
                                                int* __restrict__ bcnt) {
    __shared__ int hist[256];
    int tid = threadIdx.x;
    hist[tid] = 0;
    __syncthreads();
    int e0 = blockIdx.x * EPB1;
    int n  = min(EPB1, N_EDGES - e0);
    for (int k = tid; k < n; k += 256)
        atomicAdd(&hist[dst[e0 + k] >> BSH], 1);
    __syncthreads();
    int c = hist[tid];
    if (c) atomicAdd(&bcnt[tid], c);
}

// ---------------- scan 196 bucket counts -> bstart, init global cursors ----------------
__global__ __launch_bounds__(256) void k_bscan(const int* __restrict__ bcnt,
                                               int* __restrict__ bstart,
                                               int* __restrict__ bcur) {
    __shared__ int s[256];
    int tid = threadIdx.x;
    int c = bcnt[tid];
    s[tid] = c;
    __syncthreads();
    for (int off = 1; off < 256; off <<= 1) {
        int t = (tid >= off) ? s[tid - off] : 0;
        __syncthreads();
        s[tid] += t;
        __syncthreads();
    }
    if (tid == 0) bstart[0] = 0;
    bstart[tid + 1] = s[tid];          // inclusive -> bstart[b+1]
    bcur[tid]       = s[tid] - c;      // exclusive base, running cursor
}

// ---------------- bucket scatter: block reserves contiguous runs (coalesced writes) ----------
__global__ __launch_bounds__(256) void k_bscatter(const int* __restrict__ src,
                                                  const int* __restrict__ dst,
                                                  int* __restrict__ bcur,
                                                  unsigned int* __restrict__ ebuf) {
    __shared__ unsigned int pk[EPB2];
    __shared__ unsigned char bb[EPB2];
    __shared__ int hist[256], base[256], lcur[256];
    int tid = threadIdx.x;
    hist[tid] = 0; lcur[tid] = 0;
    __syncthreads();
    int e0 = blockIdx.x * EPB2;
    int n  = min(EPB2, N_EDGES - e0);
    for (int k = tid; k < n; k += 256) {
        int d = dst[e0 + k];
        int b = d >> BSH;
        pk[k] = ((unsigned int)src[e0 + k] << BSH) | (unsigned int)(d & (BNODES - 1));
        bb[k] = (unsigned char)b;
        atomicAdd(&hist[b], 1);
    }
    __syncthreads();
    int h = hist[tid];
    base[tid] = h ? atomicAdd(&bcur[tid], h) : 0;   // one global atomic per touched bucket
    __syncthreads();
    for (int k = tid; k < n; k += 256) {
        int b = bb[k];
        int pos = atomicAdd(&lcur[b], 1);
        ebuf[base[b] + pos] = pk[k];                // block-private run -> L2 write-combine
    }
}

// ---------------- per-bucket LDS counting sort: csr_src + rowstart + dinv ----------------
__global__ __launch_bounds__(512) void k_bsort(const int* __restrict__ bstart,
                                               const unsigned int* __restrict__ ebuf,
                                               int* __restrict__ rowstart,
                                               float* __restrict__ dinv,
                                               int* __restrict__ csr_src) {
    __shared__ int hist[512], cur[512];
    int tid = threadIdx.x;
    int b   = blockIdx.x;
    int e0 = bstart[b], e1 = bstart[b + 1];
    hist[tid] = 0;
    __syncthreads();
    for (int i = e0 + tid; i < e1; i += 512)
        atomicAdd(&hist[ebuf[i] & (BNODES - 1)], 1);
    __syncthreads();
    int deg = hist[tid];
    for (int off = 1; off < 512; off <<= 1) {       // inclusive Hillis-Steele
        int t = (tid >= off) ? hist[tid - off] : 0;
        __syncthreads();
        hist[tid] += t;
        __syncthreads();
    }
    int excl = hist[tid] - deg;
    int node = (b << BSH) + tid;
    if (node < N_NODES) {
        rowstart[node] = e0 + excl;
        dinv[node]     = rsqrtf((float)(deg + 1)); // +1 self-loop
    }
    cur[tid] = excl;
    __syncthreads();
    for (int i = e0 + tid; i < e1; i += 512) {
        unsigned int p = ebuf[i];
        int pos = atomicAdd(&cur[p & (BNODES - 1)], 1);
        csr_src[e0 + pos] = (int)(p >> BSH);        // block-private region
    }
}

// ---------------- layer-1 GEMM: h1s = (x @ W1) * dinv[n] ----------------
__global__ __launch_bounds__(256) void k_gemm1(
    const float* __restrict__ x, const float* __restrict__ W1,
    const float* __restrict__ dinv, float* __restrict__ h1s) {
    __shared__ float Xs[256 * 33];
    const int tid = threadIdx.x;
    const int n0  = blockIdx.x * 256;
    const int n   = n0 + tid;

    float acc[16];
#pragma unroll
    for (int j = 0; j < 16; ++j) acc[j] = 0.f;

    for (int kc = 0; kc < IN_DIM; kc += 32) {
        __syncthreads();
#pragma unroll
        for (int r = 0; r < 8; ++r) {
            int flat = r * 256 + tid;
            int row  = flat >> 3;
            int col  = (flat & 7) << 2;
            int gn   = n0 + row;
            if (gn < N_NODES) {
                const float4 v = *(const float4*)(x + (size_t)gn * IN_DIM + kc + col);
                float* d = &Xs[row * 33 + col];
                d[0] = v.x; d[1] = v.y; d[2] = v.z; d[3] = v.w;
            }
        }
        __syncthreads();
        if (n < N_NODES) {
#pragma unroll
            for (int i = 0; i < 32; ++i) {
                float xv = Xs[tid * 33 + i];
                const float* wr = W1 + (size_t)(kc + i) * 16;
#pragma unroll
                for (int j = 0; j < 16; ++j) acc[j] = fmaf(xv, wr[j], acc[j]);
            }
        }
    }

    if (n < N_NODES) {
        float di = dinv[n];
#pragma unroll
        for (int j = 0; j < 16; j += 4) {
            *(float4*)(h1s + (size_t)n * 16 + j) =
                make_float4(acc[j] * di, acc[j+1] * di, acc[j+2] * di, acc[j+3] * di);
        }
    }
}

// ---------------- layer-1 gather-aggregate + bias + relu ----------------
__global__ __launch_bounds__(256) void k_agg1(
    const int* __restrict__ rowstart, const int* __restrict__ csr_src,
    const float* __restrict__ h1s, const float* __restrict__ dinv,
    const float* __restrict__ b1, float* __restrict__ z) {
    int gid = blockIdx.x * 256 + threadIdx.x;
    int g = gid >> 4, j = gid & 15;
    bool valid = g < N_NODES;
    int n = valid ? g : (N_NODES - 1);
    int start = rowstart[n], end = rowstart[n + 1];
    float acc = h1s[(size_t)n * 16 + j];   // self-loop term
#pragma unroll 4
    for (int i = start; i < end; ++i) {
        int s = csr_src[i];
        acc += h1s[(size_t)s * 16 + j];
    }
    if (valid) {
        float v = dinv[n] * acc + b1[j];
        z[(size_t)n * 16 + j] = fmaxf(v, 0.f);
    }
}

// ---------------- layer-2 GEMM: h2s = (z @ W2) * dinv, padded stride 8 ----------------
__global__ __launch_bounds__(256) void k_layer2(
    const float* __restrict__ z, const float* __restrict__ W2,
    const float* __restrict__ dinv, float* __restrict__ h2s) {
    int n = blockIdx.x * 256 + threadIdx.x;
    if (n >= N_NODES) return;
    float zv[16];
#pragma unroll
    for (int k = 0; k < 16; k += 4) {
        float4 v = *(const float4*)(z + (size_t)n * 16 + k);
        zv[k] = v.x; zv[k+1] = v.y; zv[k+2] = v.z; zv[k+3] = v.w;
    }
    float di = dinv[n];
    float o[8];
#pragma unroll
    for (int jj = 0; jj < 7; ++jj) {
        float a = 0.f;
#pragma unroll
        for (int k = 0; k < 16; ++k) a = fmaf(zv[k], W2[k * 7 + jj], a);
        o[jj] = a * di;
    }
    o[7] = 0.f;
    *(float4*)(h2s + (size_t)n * 8 + 0) = make_float4(o[0], o[1], o[2], o[3]);
    *(float4*)(h2s + (size_t)n * 8 + 4) = make_float4(o[4], o[5], o[6], o[7]);
}

// ---------------- layer-2 gather-aggregate + bias + log_softmax ----------------
__global__ __launch_bounds__(256) void k_agg2(
    const int* __restrict__ rowstart, const int* __restrict__ csr_src,
    const float* __restrict__ h2s, const float* __restrict__ dinv,
    const float* __restrict__ b2, float* __restrict__ out) {
    int gid = blockIdx.x * 256 + threadIdx.x;
    int g = gid >> 3, j = gid & 7;
    bool valid = g < N_NODES;
    int n = valid ? g : (N_NODES - 1);
    int start = rowstart[n], end = rowstart[n + 1];
    float acc = h2s[(size_t)n * 8 + j];    // self-loop term (slot 7 reads 0)
#pragma unroll 4
    for (int i = start; i < end; ++i) {
        int s = csr_src[i];
        acc += h2s[(size_t)s * 8 + j];
    }
    float v = dinv[n] * acc + ((j < 7) ? b2[j] : -1e30f);
    float m = v;
    m = fmaxf(m, __shfl_xor(m, 1));
    m = fmaxf(m, __shfl_xor(m, 2));
    m = fmaxf(m, __shfl_xor(m, 4));
    float e = (j < 7) ? expf(v - m) : 0.f;
    float ssum = e;
    ssum += __shfl_xor(ssum, 1);
    ssum += __shfl_xor(ssum, 2);
    ssum += __shfl_xor(ssum, 4);
    float ls = logf(ssum) + m;
    if (valid && j < 7) out[(size_t)n * 7 + j] = v - ls;
}

extern "C" void kernel_launch(void* const* d_in, const int* in_sizes, int n_in,
                              void* d_out, int out_size, void* d_ws, size_t ws_size,
                              hipStream_t stream) {
    const float* x  = (const float*)d_in[0];
    const int*   ei = (const int*)d_in[1];
    const float* W1 = (const float*)d_in[2];
    const float* b1 = (const float*)d_in[3];
    const float* W2 = (const float*)d_in[4];
    const float* b2 = (const float*)d_in[5];
    float* out = (float*)d_out;

    const int* src = ei;             // edge_index[0]
    const int* dst = ei + N_EDGES;   // edge_index[1]

    char* ws = (char*)d_ws;
    size_t o = 0;
    auto alloc = [&](size_t bytes) -> void* {
        void* p = ws + o;
        o = (o + bytes + 255) & ~(size_t)255;
        return p;
    };
    int*   bcnt     = (int*)alloc(256 * 4);
    int*   bstart   = (int*)alloc(257 * 4);
    int*   bcur     = (int*)alloc(256 * 4);
    int*   rowstart = (int*)alloc(((size_t)N_NODES + 1) * 4);
    float* dinv     = (float*)alloc((size_t)N_NODES * 4);
    int*   csr_src  = (int*)alloc((size_t)N_EDGES * 4);
    // union: ebuf (dead after k_bsort) overlaps h1s+z (live after k_bsort)
    char*  uni      = (char*)alloc((size_t)N_EDGES * 4);   // 12.8MB = 16N*4 + 16N*4
    unsigned int* ebuf = (unsigned int*)uni;
    float* h1s      = (float*)uni;
    float* z        = h1s + (size_t)N_NODES * 16;
    float* h2s      = (float*)alloc((size_t)N_NODES * 8 * 4);

    const int nb_n = (N_NODES + 255) / 256;

    k_zero    <<<1, 256, 0, stream>>>(bcnt, rowstart);
    k_bcount  <<<NBLK1, 256, 0, stream>>>(dst, bcnt);
    k_bscan   <<<1, 256, 0, stream>>>(bcnt, bstart, bcur);
    k_bscatter<<<NBLK2, 256, 0, stream>>>(src, dst, bcur, ebuf);
    k_bsort   <<<NB, 512, 0, stream>>>(bstart, ebuf, rowstart, dinv, csr_src);
    k_gemm1   <<<nb_n, 256, 0, stream>>>(x, W1, dinv, h1s);
    k_agg1    <<<(N_NODES * 16 + 255) / 256, 256, 0, stream>>>(rowstart, csr_src, h1s, dinv, b1, z);
    k_layer2  <<<nb_n, 256, 0, stream>>>(z, W2, dinv, h2s);
    k_agg2    <<<(N_NODES * 8 + 255) / 256, 256, 0, stream>>>(rowstart, csr_src, h2s, dinv, b2, out);
}